// Round 2
// baseline (2324.524 us; speedup 1.0000x reference)
//
#include <hip/hip_runtime.h>
#include <cstdint>
#include <cstddef>

// ---- problem constants (fixed by setup_inputs) ----
#define B_   8
#define N_   8192
#define S_   2048
#define C1_  128
#define C2_  256
#define CIN_ 384      // C1 + C2
#define M_   65536    // B_ * N_
#define NOUT_ 512

typedef unsigned short u16;
typedef __attribute__((ext_vector_type(8))) short short8;
typedef __attribute__((ext_vector_type(4))) float f32x4;

__device__ __forceinline__ u16 f2bf(float f) {
  uint32_t u = __float_as_uint(f);
  u += 0x7fffu + ((u >> 16) & 1u);   // RNE
  return (u16)(u >> 16);
}
__device__ __forceinline__ float bf2f(u16 h) {
  return __uint_as_float(((uint32_t)h) << 16);
}
__device__ __forceinline__ void gload16(const void* g, void* l) {
  __builtin_amdgcn_global_load_lds(
      (const __attribute__((address_space(1))) uint32_t*)g,
      (__attribute__((address_space(3))) uint32_t*)l, 16, 0, 0);
}

// =====================================================================
// Kernel 1: 3-NN interpolation + concat -> xhl (M x [hi384|lo384] bf16)
// Distance math identical to round-1 (absmax anchor).
// =====================================================================
__global__ __launch_bounds__(256) void interp_kernel(
    const float* __restrict__ xyz1, const float* __restrict__ xyz2,
    const float* __restrict__ points1, const float* __restrict__ points2,
    u16* __restrict__ xhl)
{
  __shared__ float sx[S_], sy[S_], sz[S_], sn[S_];
  __shared__ int   sIdx[256 * 3];
  __shared__ float sWgt[256 * 3];
  const int b  = blockIdx.y;
  const int n0 = blockIdx.x * 256;
  const int t  = threadIdx.x;

  const float* xb2 = xyz2 + (size_t)b * S_ * 3;
  for (int i = t; i < S_; i += 256) {
    float px = xb2[i * 3 + 0], py = xb2[i * 3 + 1], pz = xb2[i * 3 + 2];
    sx[i] = px; sy[i] = py; sz[i] = pz;
    sn[i] = __fadd_rn(__fadd_rn(__fmul_rn(px, px), __fmul_rn(py, py)), __fmul_rn(pz, pz));
  }
  __syncthreads();

  const int n = n0 + t;
  const float* p1 = xyz1 + ((size_t)b * N_ + n) * 3;
  const float ax = p1[0], ay = p1[1], az = p1[2];
  const float nrm1 = __fadd_rn(__fadd_rn(__fmul_rn(ax, ax), __fmul_rn(ay, ay)), __fmul_rn(az, az));

  float d0 = 3.0e38f, d1 = 3.0e38f, d2 = 3.0e38f;
  int   i0 = 0, i1 = 0, i2 = 0;
  #pragma unroll 4
  for (int j = 0; j < S_; ++j) {
    float ab = __fmaf_rn(az, sz[j], __fmaf_rn(ay, sy[j], __fmul_rn(ax, sx[j])));
    float d  = __fadd_rn(__fadd_rn(nrm1, sn[j]), __fmul_rn(-2.0f, ab));
    if (d < d2) {
      if (d < d1) {
        d2 = d1; i2 = i1;
        if (d < d0) { d1 = d0; i1 = i0; d0 = d; i0 = j; }
        else        { d1 = d;  i1 = j; }
      } else { d2 = d; i2 = j; }
    }
  }
  d0 = fmaxf(d0, 0.0f); d1 = fmaxf(d1, 0.0f); d2 = fmaxf(d2, 0.0f);
  float w0 = 1.0f / (d0 + 1e-8f);
  float w1 = 1.0f / (d1 + 1e-8f);
  float w2 = 1.0f / (d2 + 1e-8f);
  float wsum = __fadd_rn(__fadd_rn(w0, w1), w2);
  w0 /= wsum; w1 /= wsum; w2 /= wsum;
  sIdx[t * 3 + 0] = i0; sIdx[t * 3 + 1] = i1; sIdx[t * 3 + 2] = i2;
  sWgt[t * 3 + 0] = w0; sWgt[t * 3 + 1] = w1; sWgt[t * 3 + 2] = w2;
  __syncthreads();

  // phase 2: coalesced gather; thread = channel (interp features, cols 128..383)
  const float* p2b = points2 + (size_t)b * S_ * C2_;
  u16* xb = xhl + ((size_t)b * N_ + n0) * 768;
  for (int p = 0; p < 256; ++p) {
    int   j0 = sIdx[p * 3 + 0], j1 = sIdx[p * 3 + 1], j2 = sIdx[p * 3 + 2];
    float v0 = sWgt[p * 3 + 0], v1 = sWgt[p * 3 + 1], v2 = sWgt[p * 3 + 2];
    float f = __fadd_rn(__fadd_rn(__fmul_rn(p2b[(size_t)j0 * C2_ + t], v0),
                                  __fmul_rn(p2b[(size_t)j1 * C2_ + t], v1)),
                        __fmul_rn(p2b[(size_t)j2 * C2_ + t], v2));
    u16 h = f2bf(f);
    xb[(size_t)p * 768 + 128 + t] = h;                      // hi
    xb[(size_t)p * 768 + 512 + t] = f2bf(f - bf2f(h));      // lo (384 + 128 + t)
  }
  // points1 into cols 0..127
  const float* q1 = points1 + ((size_t)b * N_ + n0) * C1_;
  for (int it = 0; it < 128; ++it) {
    int idx = it * 256 + t;
    int p = idx >> 7, c = idx & 127;
    float v = q1[idx];
    u16 h = f2bf(v);
    xb[(size_t)p * 768 + c] = h;
    xb[(size_t)p * 768 + 384 + c] = f2bf(v - bf2f(h));
  }
}

// =====================================================================
// Kernel 2: W fp32 -> [hi K | lo K] bf16 rows
// =====================================================================
__global__ __launch_bounds__(128) void wconv_kernel(
    const float* __restrict__ W, u16* __restrict__ Whl, int K)
{
  int c = blockIdx.x * 128 + threadIdx.x;
  int o = blockIdx.y;
  float w = W[(size_t)o * K + c];
  u16 h = f2bf(w);
  Whl[(size_t)o * 2 * K + c] = h;
  Whl[(size_t)o * 2 * K + K + c] = f2bf(w - bf2f(h));
}

// =====================================================================
// Kernel 3: bf16-split MFMA GEMM.  Y[M,512] = A[M,K]*W[512,K]^T + bias
//   A, W stored as [hi K | lo K] bf16 rows.  acc += Ah*Wh + Ah*Wl + Al*Wh.
//   BN stats (sum/sumsq of y incl. bias) fused via LDS + global atomics.
//   Output written as bf16 hi/lo pairs ([hi512|lo512] per row).
//   BNIN: A is y1hl; staging reconstructs fp32, applies BN1+ReLU, re-splits.
//   BN(block) = 512 (full width) => A read once; in-place-safe for GEMM2.
// Tile: BM x 512, BK=32, threads = BM*4 (wave tile 64x128, 16x16x32 MFMA).
// LDS slots XOR-swizzled (slot ^= (row ^ row>>2) & 3) for conflict-free
// ds_read_b128; gload_lds path pre-swizzles the *global* source address.
// =====================================================================
template<int K, bool BNIN, int BM>
__global__ __launch_bounds__(BM * 4, 4) void gemm_kernel(
    const u16* __restrict__ A, const u16* __restrict__ W,
    const float* __restrict__ bias,
    const float* __restrict__ aSc, const float* __restrict__ aSh,
    u16* __restrict__ Yhl, float* __restrict__ sumOut, float* __restrict__ sqOut)
{
  constexpr int T   = BM * 4;
  constexpr int BPT = 2048 / T;        // B 16B-units per dtype per thread
  constexpr int SA  = 2 * K;           // A row stride (u16)
  constexpr int SW  = 2 * K;
  constexpr uint32_t ALO = BM * 64;
  constexpr uint32_t BHI = BM * 128;
  constexpr uint32_t BLO = BM * 128 + 32768;
  constexpr uint32_t SCOFF = BM * 128 + 65536;
  static_assert(K % 32 == 0, "");

  extern __shared__ char smem[];
  const int t  = threadIdx.x;
  const int m0 = blockIdx.x * BM;

  const int l   = t & 63;
  const int lr  = l & 15;
  const int lq  = l >> 4;
  const int ps  = (lq ^ (l & 3) ^ ((l >> 2) & 3)) & 3;  // swizzled phys slot for frag reads
  const int wid = t >> 6;
  const int wm  = wid >> 2;
  const int wn  = wid & 3;

  // ---- staging address setup ----
  const int arow = t >> 2;                                  // 0..BM-1 (T == BM*4)
  const int aswz = ((arow ^ (arow >> 2)) & 3);
  const u16* pAhi;
  if constexpr (!BNIN) {
    int s = (t & 3) ^ aswz;                                 // pre-swizzled source slot
    pAhi = A + (size_t)(m0 + arow) * SA + s * 8;
  } else {
    pAhi = A + (size_t)(m0 + arow) * SA + (t & 3) * 8;      // linear read; swizzle on ds_write
  }
  const u16* pAlo = pAhi + K;
  const uint32_t aLdsHi = (uint32_t)t * 16;
  const uint32_t aLdsLo = ALO + (uint32_t)t * 16;
  const uint32_t aWr = (uint32_t)arow * 64 + (uint32_t)(((t & 3) ^ aswz) * 16);

  const u16* pB[2 * BPT];
  uint32_t bLds[2 * BPT];
  #pragma unroll
  for (int j = 0; j < BPT; ++j) {
    int u = j * T + t;                   // 0..2047
    int row = u >> 2;
    int s = (u & 3) ^ ((row ^ (row >> 2)) & 3);
    pB[j] = W + (size_t)row * SW + s * 8;
    bLds[j] = BHI + (uint32_t)u * 16;
    pB[BPT + j] = pB[j] + K;
    bLds[BPT + j] = BLO + (uint32_t)u * 16;
  }

  if constexpr (BNIN) {
    for (int i = t; i < 512; i += T) {
      *(float*)(smem + SCOFF + i * 4) = aSc[i];
      *(float*)(smem + SCOFF + 2048 + i * 4) = aSh[i];
    }
  }
  __syncthreads();

  f32x4 acc[4][8];
  #pragma unroll
  for (int i = 0; i < 4; ++i)
    #pragma unroll
    for (int j = 0; j < 8; ++j) acc[i][j] = (f32x4){0.f, 0.f, 0.f, 0.f};

  for (int kt = 0; kt < K; kt += 32) {
    // ---- stage B via global_load_lds ----
    #pragma unroll
    for (int j = 0; j < 2 * BPT; ++j) gload16(pB[j] + kt, smem + bLds[j]);
    // ---- stage A ----
    if constexpr (!BNIN) {
      gload16(pAhi + kt, smem + aLdsHi);
      gload16(pAlo + kt, smem + aLdsLo);
    } else {
      short8 h8 = *(const short8*)(pAhi + kt);
      short8 l8 = *(const short8*)(pAlo + kt);
      const float* scp = (const float*)(smem + SCOFF) + kt + (t & 3) * 8;
      const float* shp = (const float*)(smem + SCOFF + 2048) + kt + (t & 3) * 8;
      short8 hv, lv;
      #pragma unroll
      for (int j = 0; j < 8; ++j) {
        float y = bf2f((u16)h8[j]) + bf2f((u16)l8[j]);
        float v = fmaxf(__fmaf_rn(y, scp[j], shp[j]), 0.0f);
        u16 h = f2bf(v);
        hv[j] = (short)h;
        lv[j] = (short)f2bf(v - bf2f(h));
      }
      *(short8*)(smem + aWr) = hv;
      *(short8*)(smem + ALO + aWr) = lv;
    }
    __syncthreads();
    // ---- compute ----
    short8 ah[4], al[4], bh[8], bl[8];
    const uint32_t abase = (uint32_t)(wm * 64 + lr) * 64 + (uint32_t)ps * 16;
    #pragma unroll
    for (int mi = 0; mi < 4; ++mi) {
      ah[mi] = *(const short8*)(smem + abase + mi * 1024);
      al[mi] = *(const short8*)(smem + ALO + abase + mi * 1024);
    }
    const uint32_t bbase = BHI + (uint32_t)(wn * 128 + lr) * 64 + (uint32_t)ps * 16;
    #pragma unroll
    for (int ni = 0; ni < 8; ++ni) {
      bh[ni] = *(const short8*)(smem + bbase + ni * 1024);
      bl[ni] = *(const short8*)(smem + bbase + 32768 + ni * 1024);
    }
    #pragma unroll
    for (int mi = 0; mi < 4; ++mi)
      #pragma unroll
      for (int ni = 0; ni < 8; ++ni) {
        acc[mi][ni] = __builtin_amdgcn_mfma_f32_16x16x32_bf16(ah[mi], bh[ni], acc[mi][ni], 0, 0, 0);
        acc[mi][ni] = __builtin_amdgcn_mfma_f32_16x16x32_bf16(ah[mi], bl[ni], acc[mi][ni], 0, 0, 0);
        acc[mi][ni] = __builtin_amdgcn_mfma_f32_16x16x32_bf16(al[mi], bh[ni], acc[mi][ni], 0, 0, 0);
      }
    __syncthreads();
  }

  // ---- epilogue: bias, hi/lo store, fused BN stats ----
  float* sred = (float*)smem;              // [0..511]=sum, [512..1023]=sumsq
  for (int i = t; i < 1024; i += T) sred[i] = 0.f;
  __syncthreads();

  float bvals[8];
  #pragma unroll
  for (int ni = 0; ni < 8; ++ni) bvals[ni] = bias[wn * 128 + ni * 16 + lr];

  float colS[8], colQ[8];
  #pragma unroll
  for (int ni = 0; ni < 8; ++ni) { colS[ni] = 0.f; colQ[ni] = 0.f; }

  #pragma unroll
  for (int mi = 0; mi < 4; ++mi) {
    #pragma unroll
    for (int q = 0; q < 4; ++q) {
      int m = m0 + wm * 64 + mi * 16 + lq * 4 + q;
      size_t rowb = (size_t)m * 1024;
      #pragma unroll
      for (int ni = 0; ni < 8; ++ni) {
        int col = wn * 128 + ni * 16 + lr;
        float v = acc[mi][ni][q] + bvals[ni];
        u16 h = f2bf(v);
        Yhl[rowb + col] = h;
        Yhl[rowb + 512 + col] = f2bf(v - bf2f(h));
        colS[ni] += v;
        colQ[ni] = __fmaf_rn(v, v, colQ[ni]);
      }
    }
  }
  #pragma unroll
  for (int ni = 0; ni < 8; ++ni) {
    int col = wn * 128 + ni * 16 + lr;
    atomicAdd(&sred[col], colS[ni]);
    atomicAdd(&sred[512 + col], colQ[ni]);
  }
  __syncthreads();
  for (int i = t; i < 512; i += T) {
    atomicAdd(&sumOut[i], sred[i]);
    atomicAdd(&sqOut[i], sred[512 + i]);
  }
}

// =====================================================================
// Kernel 4: BN stats -> scale/shift
// =====================================================================
__global__ void finalize_kernel(const float* __restrict__ sum, const float* __restrict__ sq,
                                const float* __restrict__ g, const float* __restrict__ be,
                                float* __restrict__ scale, float* __restrict__ shift)
{
  int c = blockIdx.x * 256 + threadIdx.x;
  if (c >= 512) return;
  const float invM = 1.0f / 65536.0f;
  float mean = sum[c] * invM;
  float var  = fmaxf(sq[c] * invM - mean * mean, 0.0f);
  float rstd = rsqrtf(var + 1e-5f);
  float sc   = g[c] * rstd;
  scale[c] = sc;
  shift[c] = __fmaf_rn(-mean, sc, be[c]);
}

// =====================================================================
// Kernel 5: final BN+ReLU, in-place on d_out (bf16 hi/lo row -> fp32 row).
// One block per row; read all before write (syncthreads).
// =====================================================================
__global__ __launch_bounds__(256) void bnrelu_kernel(
    u16* __restrict__ y, const float* __restrict__ sc, const float* __restrict__ sh)
{
  const size_t row = blockIdx.x;
  u16* ru = y + row * 1024;
  const int t = threadIdx.x;
  u16 h0 = ru[2 * t], h1 = ru[2 * t + 1];
  u16 l0 = ru[512 + 2 * t], l1 = ru[512 + 2 * t + 1];
  float2 scv = *(const float2*)(sc + 2 * t);
  float2 shv = *(const float2*)(sh + 2 * t);
  float v0 = bf2f(h0) + bf2f(l0);
  float v1 = bf2f(h1) + bf2f(l1);
  float o0 = fmaxf(__fmaf_rn(v0, scv.x, shv.x), 0.0f);
  float o1 = fmaxf(__fmaf_rn(v1, scv.y, shv.y), 0.0f);
  __syncthreads();
  *(float2*)((float*)ru + 2 * t) = make_float2(o0, o1);
}

// =====================================================================
extern "C" void kernel_launch(void* const* d_in, const int* in_sizes, int n_in,
                              void* d_out, int out_size, void* d_ws, size_t ws_size,
                              hipStream_t stream)
{
  const float* xyz1    = (const float*)d_in[0];
  const float* xyz2    = (const float*)d_in[1];
  const float* points1 = (const float*)d_in[2];
  const float* points2 = (const float*)d_in[3];
  const float* W1  = (const float*)d_in[4];
  const float* b1  = (const float*)d_in[5];
  const float* g1  = (const float*)d_in[6];
  const float* be1 = (const float*)d_in[7];
  const float* W2  = (const float*)d_in[8];
  const float* b2  = (const float*)d_in[9];
  const float* g2  = (const float*)d_in[10];
  const float* be2 = (const float*)d_in[11];

  char* wsb = (char*)d_ws;
  float* wsf = (float*)d_ws;
  float* sum1 = wsf + 0,    *sq1 = wsf + 512,  *sc1 = wsf + 1024, *sh1 = wsf + 1536;
  float* sum2 = wsf + 2048, *sq2 = wsf + 2560, *sc2 = wsf + 3072, *sh2 = wsf + 3584;
  u16* w1hl = (u16*)(wsb + 16384);              // 512x768  bf16 (786 KB)
  u16* w2hl = (u16*)(wsb + 802816);             // 512x1024 bf16 (1 MB)
  u16* xhl  = (u16*)(wsb + 1851392);            // M x 768  bf16 (100.7 MB)
  u16* y1hl = (u16*)d_out;                      // M x [hi512|lo512], then y2hl in-place

  // allow >64KB dynamic LDS (no-op if already permitted)
  (void)hipFuncSetAttribute((const void*)gemm_kernel<CIN_,  false, 128>,
                            hipFuncAttributeMaxDynamicSharedMemorySize, 81920);
  (void)hipFuncSetAttribute((const void*)gemm_kernel<NOUT_, true,  256>,
                            hipFuncAttributeMaxDynamicSharedMemorySize, 102400);

  hipMemsetAsync(d_ws, 0, 16384, stream);

  wconv_kernel<<<dim3(CIN_ / 128, 512), 128, 0, stream>>>(W1, w1hl, CIN_);
  wconv_kernel<<<dim3(NOUT_ / 128, 512), 128, 0, stream>>>(W2, w2hl, NOUT_);

  interp_kernel<<<dim3(N_ / 256, B_), 256, 0, stream>>>(xyz1, xyz2, points1, points2, xhl);

  gemm_kernel<CIN_, false, 128><<<dim3(M_ / 128), 512, 81920, stream>>>(
      xhl, w1hl, b1, nullptr, nullptr, y1hl, sum1, sq1);

  finalize_kernel<<<2, 256, 0, stream>>>(sum1, sq1, g1, be1, sc1, sh1);

  gemm_kernel<NOUT_, true, 256><<<dim3(M_ / 256), 1024, 102400, stream>>>(
      y1hl, w2hl, b2, sc1, sh1, y1hl, sum2, sq2);

  finalize_kernel<<<2, 256, 0, stream>>>(sum2, sq2, g2, be2, sc2, sh2);

  bnrelu_kernel<<<M_, 256, 0, stream>>>((u16*)d_out, sc2, sh2);
}

// Round 5
// 887.680 us; speedup vs baseline: 2.6187x; 2.6187x over previous
//
#include <hip/hip_runtime.h>
#include <cstdint>
#include <cstddef>

// ---- problem constants (fixed by setup_inputs) ----
#define B_   8
#define N_   8192
#define S_   2048
#define C1_  128
#define C2_  256
#define CIN_ 384      // C1 + C2
#define M_   65536    // B_ * N_
#define NOUT_ 512

typedef unsigned short u16;
typedef __attribute__((ext_vector_type(8))) short short8;
typedef __attribute__((ext_vector_type(4))) short short4v;
typedef __attribute__((ext_vector_type(4))) float f32x4;

__device__ __forceinline__ u16 f2bf(float f) {       // RNE
  uint32_t u = __float_as_uint(f);
  u += 0x7fffu + ((u >> 16) & 1u);
  return (u16)(u >> 16);
}
__device__ __forceinline__ float bf2f(u16 h) {
  return __uint_as_float(((uint32_t)h) << 16);
}
// hi = truncated top-16 (error compensated exactly by lo), lo = RNE remainder.
// total representation error ~2^-17 relative.
__device__ __forceinline__ void split2(float v, u16& h, u16& l) {
  uint32_t u = __float_as_uint(v);
  h = (u16)(u >> 16);
  float hf = __uint_as_float(u & 0xffff0000u);
  l = f2bf(v - hf);
}
__device__ __forceinline__ void gload16(const void* g, void* l) {
  __builtin_amdgcn_global_load_lds(
      (const __attribute__((address_space(1))) uint32_t*)g,
      (__attribute__((address_space(3))) uint32_t*)l, 16, 0, 0);
}

// =====================================================================
// Kernel 1: 3-NN interpolation + concat -> xhl (M rows of [hi384|lo384])
// 128 threads, 2 queries/thread; packed float4 LDS (1 broadcast read/j).
// Distance & weight arithmetic identical to round-1 (absmax anchor).
// =====================================================================
__global__ __launch_bounds__(128) void interp_kernel(
    const float* __restrict__ xyz1, const float* __restrict__ xyz2,
    const float* __restrict__ points1, const float* __restrict__ points2,
    u16* __restrict__ xhl)
{
  __shared__ float4 s4[S_];          // 32 KB
  __shared__ int    sIdx[256 * 3];
  __shared__ float  sWgt[256 * 3];
  const int b  = blockIdx.y;
  const int n0 = blockIdx.x * 256;
  const int t  = threadIdx.x;

  const float* xb2 = xyz2 + (size_t)b * S_ * 3;
  for (int i = t; i < S_; i += 128) {
    float px = xb2[i * 3 + 0], py = xb2[i * 3 + 1], pz = xb2[i * 3 + 2];
    float nn = __fadd_rn(__fadd_rn(__fmul_rn(px, px), __fmul_rn(py, py)), __fmul_rn(pz, pz));
    s4[i] = make_float4(px, py, pz, nn);
  }
  __syncthreads();

  // two queries: qa = n0 + t, qb = n0 + 128 + t
  const float* pa = xyz1 + ((size_t)b * N_ + n0 + t) * 3;
  const float* pb = xyz1 + ((size_t)b * N_ + n0 + 128 + t) * 3;
  const float ax = pa[0], ay = pa[1], az = pa[2];
  const float bx = pb[0], by = pb[1], bz = pb[2];
  const float na = __fadd_rn(__fadd_rn(__fmul_rn(ax, ax), __fmul_rn(ay, ay)), __fmul_rn(az, az));
  const float nb = __fadd_rn(__fadd_rn(__fmul_rn(bx, bx), __fmul_rn(by, by)), __fmul_rn(bz, bz));

  float a0 = 3.0e38f, a1 = 3.0e38f, a2 = 3.0e38f;
  float c0 = 3.0e38f, c1 = 3.0e38f, c2 = 3.0e38f;
  int   ia0 = 0, ia1 = 0, ia2 = 0, ic0 = 0, ic1 = 0, ic2 = 0;
  for (int j = 0; j < S_; ++j) {
    float4 p = s4[j];
    float abd = __fmaf_rn(az, p.z, __fmaf_rn(ay, p.y, __fmul_rn(ax, p.x)));
    float da  = __fadd_rn(__fadd_rn(na, p.w), __fmul_rn(-2.0f, abd));
    float cbd = __fmaf_rn(bz, p.z, __fmaf_rn(by, p.y, __fmul_rn(bx, p.x)));
    float dc  = __fadd_rn(__fadd_rn(nb, p.w), __fmul_rn(-2.0f, cbd));
    if (da < a2) {
      if (da < a1) {
        a2 = a1; ia2 = ia1;
        if (da < a0) { a1 = a0; ia1 = ia0; a0 = da; ia0 = j; }
        else         { a1 = da; ia1 = j; }
      } else { a2 = da; ia2 = j; }
    }
    if (dc < c2) {
      if (dc < c1) {
        c2 = c1; ic2 = ic1;
        if (dc < c0) { c1 = c0; ic1 = ic0; c0 = dc; ic0 = j; }
        else         { c1 = dc; ic1 = j; }
      } else { c2 = dc; ic2 = j; }
    }
  }
  {
    float d0 = fmaxf(a0, 0.f), d1 = fmaxf(a1, 0.f), d2 = fmaxf(a2, 0.f);
    float w0 = 1.0f / (d0 + 1e-8f), w1 = 1.0f / (d1 + 1e-8f), w2 = 1.0f / (d2 + 1e-8f);
    float ws = __fadd_rn(__fadd_rn(w0, w1), w2);
    sIdx[t * 3 + 0] = ia0; sIdx[t * 3 + 1] = ia1; sIdx[t * 3 + 2] = ia2;
    sWgt[t * 3 + 0] = w0 / ws; sWgt[t * 3 + 1] = w1 / ws; sWgt[t * 3 + 2] = w2 / ws;
  }
  {
    float d0 = fmaxf(c0, 0.f), d1 = fmaxf(c1, 0.f), d2 = fmaxf(c2, 0.f);
    float w0 = 1.0f / (d0 + 1e-8f), w1 = 1.0f / (d1 + 1e-8f), w2 = 1.0f / (d2 + 1e-8f);
    float ws = __fadd_rn(__fadd_rn(w0, w1), w2);
    int u = t + 128;
    sIdx[u * 3 + 0] = ic0; sIdx[u * 3 + 1] = ic1; sIdx[u * 3 + 2] = ic2;
    sWgt[u * 3 + 0] = w0 / ws; sWgt[u * 3 + 1] = w1 / ws; sWgt[u * 3 + 2] = w2 / ws;
  }
  __syncthreads();

  // phase 2: interpolate channels; thread t covers channels t and t+128
  const float* p2b = points2 + (size_t)b * S_ * C2_;
  for (int p = 0; p < 256; ++p) {
    int   j0 = sIdx[p * 3 + 0], j1 = sIdx[p * 3 + 1], j2 = sIdx[p * 3 + 2];
    float v0 = sWgt[p * 3 + 0], v1 = sWgt[p * 3 + 1], v2 = sWgt[p * 3 + 2];
    u16* row = xhl + ((size_t)b * N_ + n0 + p) * 768;
    float fa = __fadd_rn(__fadd_rn(__fmul_rn(p2b[(size_t)j0 * C2_ + t], v0),
                                   __fmul_rn(p2b[(size_t)j1 * C2_ + t], v1)),
                         __fmul_rn(p2b[(size_t)j2 * C2_ + t], v2));
    float fb = __fadd_rn(__fadd_rn(__fmul_rn(p2b[(size_t)j0 * C2_ + 128 + t], v0),
                                   __fmul_rn(p2b[(size_t)j1 * C2_ + 128 + t], v1)),
                         __fmul_rn(p2b[(size_t)j2 * C2_ + 128 + t], v2));
    u16 h, l;
    split2(fa, h, l); row[128 + t] = h; row[384 + 128 + t] = l;
    split2(fb, h, l); row[256 + t] = h; row[384 + 256 + t] = l;
  }
  // points1 -> cols 0..127
  const float* q1 = points1 + ((size_t)b * N_ + n0) * C1_;
  for (int p = 0; p < 256; ++p) {
    float v = q1[p * 128 + t];
    u16 h, l; split2(v, h, l);
    u16* row = xhl + ((size_t)b * N_ + n0 + p) * 768;
    row[t] = h; row[384 + t] = l;
  }
}

// =====================================================================
// Kernel 2: W1 fp32 -> [hi K | lo K] bf16 rows (written into d_out head)
// =====================================================================
__global__ __launch_bounds__(128) void wconv_kernel(
    const float* __restrict__ W, u16* __restrict__ Whl, int K)
{
  int c = blockIdx.x * 128 + threadIdx.x;
  int o = blockIdx.y;
  float w = W[(size_t)o * K + c];
  u16 h, l; split2(w, h, l);
  Whl[(size_t)o * 2 * K + c] = h;
  Whl[(size_t)o * 2 * K + K + c] = l;
}

// =====================================================================
// Kernel 3: bf16-split MFMA GEMM (m97 shape).
//   Y[M,512] = A[M,K] * W[512,K]^T + bias ; acc += Ah*Wh + Ah*Wl + Al*Wh
//   A rows: [hi K | lo K] u16, stride 2K. B: BCONV ? fp32 (convert in
//   staging) : same hi/lo u16 layout.
//   Tile 128x128, BK=32, 256 thr, 4 waves 2x2, wave tile 64x64, acc[4][4].
//   Output rows: [hi512 | lo512] u16. Fused BN-stat accumulation.
// =====================================================================
template<int K, bool BCONV>
__global__ __launch_bounds__(256) void gemm_kernel(
    const u16* __restrict__ A, const u16* __restrict__ Bu,
    const float* __restrict__ Bf, const float* __restrict__ bias,
    u16* __restrict__ Y, float* __restrict__ sumOut, float* __restrict__ sqOut)
{
  __shared__ __align__(16) u16 sAh[4096], sAl[4096], sBh[4096], sBl[4096]; // 8 KB each
  __shared__ float sred[256];
  static_assert(K % 32 == 0, "");

  const int t  = threadIdx.x;
  const int n0 = blockIdx.x * 128;
  const int m0 = blockIdx.y * 128;
  const int l  = t & 63, lr = l & 15, lq = l >> 4;
  const int wid = t >> 6, wm = wid >> 1, wn = wid & 1;

  f32x4 acc[4][4];
  #pragma unroll
  for (int i = 0; i < 4; ++i)
    #pragma unroll
    for (int j = 0; j < 4; ++j) acc[i][j] = (f32x4){0.f, 0.f, 0.f, 0.f};

  for (int kt = 0; kt < K; kt += 32) {
    #pragma unroll
    for (int i = 0; i < 2; ++i) {
      int u = i * 256 + t;
      int row = u >> 2, sl = u & 3;
      const u16* srcA = A + (size_t)(m0 + row) * (2 * K) + kt + sl * 8;
      gload16(srcA,     (char*)sAh + u * 16);
      gload16(srcA + K, (char*)sAl + u * 16);
      if constexpr (!BCONV) {
        const u16* srcB = Bu + (size_t)(n0 + row) * (2 * K) + kt + sl * 8;
        gload16(srcB,     (char*)sBh + u * 16);
        gload16(srcB + K, (char*)sBl + u * 16);
      }
    }
    if constexpr (BCONV) {
      #pragma unroll
      for (int i = 0; i < 4; ++i) {
        int u = i * 256 + t;
        int row = u >> 3, c4 = (u & 7) * 4;
        float4 w4 = *(const float4*)(Bf + (size_t)(n0 + row) * K + kt + c4);
        short4v h4, l4;
        u16 h, lo;
        split2(w4.x, h, lo); h4[0] = (short)h; l4[0] = (short)lo;
        split2(w4.y, h, lo); h4[1] = (short)h; l4[1] = (short)lo;
        split2(w4.z, h, lo); h4[2] = (short)h; l4[2] = (short)lo;
        split2(w4.w, h, lo); h4[3] = (short)h; l4[3] = (short)lo;
        *(short4v*)((char*)sBh + row * 64 + c4 * 2) = h4;
        *(short4v*)((char*)sBl + row * 64 + c4 * 2) = l4;
      }
    }
    __syncthreads();

    const int abase = (wm * 64 + lr) * 64 + lq * 16;   // byte offsets
    const int bbase = (wn * 64 + lr) * 64 + lq * 16;
    short8 bh[4], bl[4];
    #pragma unroll
    for (int ni = 0; ni < 4; ++ni) {
      bh[ni] = *(const short8*)((const char*)sBh + bbase + ni * 1024);
      bl[ni] = *(const short8*)((const char*)sBl + bbase + ni * 1024);
    }
    #pragma unroll
    for (int mi = 0; mi < 4; ++mi) {
      short8 ah = *(const short8*)((const char*)sAh + abase + mi * 1024);
      short8 al = *(const short8*)((const char*)sAl + abase + mi * 1024);
      #pragma unroll
      for (int ni = 0; ni < 4; ++ni) {
        acc[mi][ni] = __builtin_amdgcn_mfma_f32_16x16x32_bf16(ah, bh[ni], acc[mi][ni], 0, 0, 0);
        acc[mi][ni] = __builtin_amdgcn_mfma_f32_16x16x32_bf16(ah, bl[ni], acc[mi][ni], 0, 0, 0);
        acc[mi][ni] = __builtin_amdgcn_mfma_f32_16x16x32_bf16(al, bh[ni], acc[mi][ni], 0, 0, 0);
      }
    }
    __syncthreads();
  }

  // ---- epilogue: bias, hi/lo store, BN stats ----
  sred[t] = 0.f;
  __syncthreads();

  float bj[4];
  #pragma unroll
  for (int ni = 0; ni < 4; ++ni) bj[ni] = bias[n0 + wn * 64 + ni * 16 + lr];

  float colS[4] = {0.f, 0.f, 0.f, 0.f}, colQ[4] = {0.f, 0.f, 0.f, 0.f};
  #pragma unroll
  for (int mi = 0; mi < 4; ++mi) {
    #pragma unroll
    for (int q = 0; q < 4; ++q) {
      int m = m0 + wm * 64 + mi * 16 + lq * 4 + q;
      u16* yr = Y + (size_t)m * 1024 + n0;
      #pragma unroll
      for (int ni = 0; ni < 4; ++ni) {
        int col = wn * 64 + ni * 16 + lr;
        float v = acc[mi][ni][q] + bj[ni];
        u16 h, lo; split2(v, h, lo);
        yr[col] = h; yr[512 + col] = lo;
        colS[ni] += v;
        colQ[ni] = __fmaf_rn(v, v, colQ[ni]);
      }
    }
  }
  #pragma unroll
  for (int ni = 0; ni < 4; ++ni) {
    int col = wn * 64 + ni * 16 + lr;
    atomicAdd(&sred[col], colS[ni]);
    atomicAdd(&sred[128 + col], colQ[ni]);
  }
  __syncthreads();
  if (t < 128) {
    atomicAdd(&sumOut[n0 + t], sred[t]);
    atomicAdd(&sqOut[n0 + t], sred[128 + t]);
  }
}

// =====================================================================
// Kernel 4: BN stats -> scale/shift
// =====================================================================
__global__ void finalize_kernel(const float* __restrict__ sum, const float* __restrict__ sq,
                                const float* __restrict__ g, const float* __restrict__ be,
                                float* __restrict__ scale, float* __restrict__ shift)
{
  int c = blockIdx.x * 256 + threadIdx.x;
  if (c >= 512) return;
  const float invM = 1.0f / 65536.0f;
  float mean = sum[c] * invM;
  float var  = fmaxf(sq[c] * invM - mean * mean, 0.0f);
  float rstd = rsqrtf(var + 1e-5f);
  float sc   = g[c] * rstd;
  scale[c] = sc;
  shift[c] = __fmaf_rn(-mean, sc, be[c]);
}

// =====================================================================
// Kernel 5: x2 = relu(bn1(y1)) in-place on y1hl (hi/lo rows), re-split.
// =====================================================================
__global__ __launch_bounds__(256) void x2_kernel(
    u16* __restrict__ y, const float* __restrict__ sc, const float* __restrict__ sh)
{
  const int total8 = M_ * 512 / 8;
  for (int i8 = blockIdx.x * 256 + threadIdx.x; i8 < total8;
       i8 += gridDim.x * 256) {
    int row = i8 >> 6, c8 = (i8 & 63) * 8;
    u16* p = y + (size_t)row * 1024 + c8;
    short8 h8 = *(const short8*)p;
    short8 l8 = *(const short8*)(p + 512);
    float4 sc0 = *(const float4*)(sc + c8), sc1v = *(const float4*)(sc + c8 + 4);
    float4 sh0 = *(const float4*)(sh + c8), sh1v = *(const float4*)(sh + c8 + 4);
    float scv[8] = {sc0.x, sc0.y, sc0.z, sc0.w, sc1v.x, sc1v.y, sc1v.z, sc1v.w};
    float shv[8] = {sh0.x, sh0.y, sh0.z, sh0.w, sh1v.x, sh1v.y, sh1v.z, sh1v.w};
    short8 ho, lo_;
    #pragma unroll
    for (int j = 0; j < 8; ++j) {
      float v = bf2f((u16)h8[j]) + bf2f((u16)l8[j]);
      float z = fmaxf(__fmaf_rn(v, scv[j], shv[j]), 0.0f);
      u16 h, lo; split2(z, h, lo);
      ho[j] = (short)h; lo_[j] = (short)lo;
    }
    *(short8*)p = ho;
    *(short8*)(p + 512) = lo_;
  }
}

// =====================================================================
// Kernel 6: final BN+ReLU, in-place (u16 hi/lo row -> fp32 row).
// =====================================================================
__global__ __launch_bounds__(256) void bnrelu_kernel(
    u16* __restrict__ y, const float* __restrict__ sc, const float* __restrict__ sh)
{
  const size_t row = blockIdx.x;
  u16* ru = y + row * 1024;
  const int t = threadIdx.x;
  u16 h0 = ru[2 * t], h1 = ru[2 * t + 1];
  u16 l0 = ru[512 + 2 * t], l1 = ru[512 + 2 * t + 1];
  float2 scv = *(const float2*)(sc + 2 * t);
  float2 shv = *(const float2*)(sh + 2 * t);
  float v0 = bf2f(h0) + bf2f(l0);
  float v1 = bf2f(h1) + bf2f(l1);
  float o0 = fmaxf(__fmaf_rn(v0, scv.x, shv.x), 0.0f);
  float o1 = fmaxf(__fmaf_rn(v1, scv.y, shv.y), 0.0f);
  __syncthreads();
  *(float2*)((float*)ru + 2 * t) = make_float2(o0, o1);
}

// =====================================================================
extern "C" void kernel_launch(void* const* d_in, const int* in_sizes, int n_in,
                              void* d_out, int out_size, void* d_ws, size_t ws_size,
                              hipStream_t stream)
{
  const float* xyz1    = (const float*)d_in[0];
  const float* xyz2    = (const float*)d_in[1];
  const float* points1 = (const float*)d_in[2];
  const float* points2 = (const float*)d_in[3];
  const float* W1  = (const float*)d_in[4];
  const float* b1  = (const float*)d_in[5];
  const float* g1  = (const float*)d_in[6];
  const float* be1 = (const float*)d_in[7];
  const float* W2  = (const float*)d_in[8];
  const float* b2  = (const float*)d_in[9];
  const float* g2  = (const float*)d_in[10];
  const float* be2 = (const float*)d_in[11];

  // ws: stats (16 KB) + y1hl (134,217,728 B) = 134,234,112 B (== round-1 proven)
  float* wsf = (float*)d_ws;
  float* sum1 = wsf + 0,    *sq1 = wsf + 512,  *sc1 = wsf + 1024, *sh1 = wsf + 1536;
  float* sum2 = wsf + 2048, *sq2 = wsf + 2560, *sc2 = wsf + 3072, *sh2 = wsf + 3584;
  u16* y1hl = (u16*)((char*)d_ws + 16384);      // M x [hi512|lo512]

  // d_out staging: w1hl [0, 786,432) ; xhl [786,432, 101,449,728)
  u16* w1hl = (u16*)d_out;
  u16* xhl  = (u16*)d_out + 393216;

  hipMemsetAsync(d_ws, 0, 16384, stream);

  wconv_kernel<<<dim3(CIN_ / 128, 512), 128, 0, stream>>>(W1, w1hl, CIN_);
  interp_kernel<<<dim3(N_ / 256, B_), 128, 0, stream>>>(xyz1, xyz2, points1, points2, xhl);

  gemm_kernel<CIN_, false><<<dim3(4, M_ / 128), 256, 0, stream>>>(
      xhl, w1hl, nullptr, b1, y1hl, sum1, sq1);

  finalize_kernel<<<2, 256, 0, stream>>>(sum1, sq1, g1, be1, sc1, sh1);

  x2_kernel<<<2048, 256, 0, stream>>>(y1hl, sc1, sh1);

  gemm_kernel<NOUT_, true><<<dim3(4, M_ / 128), 256, 0, stream>>>(
      y1hl, nullptr, W2, b2, (u16*)d_out, sum2, sq2);

  finalize_kernel<<<2, 256, 0, stream>>>(sum2, sq2, g2, be2, sc2, sh2);

  bnrelu_kernel<<<M_, 256, 0, stream>>>((u16*)d_out, sc2, sh2);
}

// Round 9
// 620.252 us; speedup vs baseline: 3.7477x; 1.4312x over previous
//
#include <hip/hip_runtime.h>
#include <cstdint>
#include <cstddef>

// ---- problem constants (fixed by setup_inputs) ----
#define B_   8
#define N_   8192
#define S_   2048
#define C1_  128
#define C2_  256
#define CIN_ 384      // C1 + C2
#define M_   65536    // B_ * N_
#define NOUT_ 512
#define SCH_ 8                 // S-chunks for knn parallelism
#define CPTS (S_ / SCH_)       // 256 points per chunk

typedef unsigned short u16;
typedef __attribute__((ext_vector_type(8))) short short8;
typedef __attribute__((ext_vector_type(4))) short short4v;
typedef __attribute__((ext_vector_type(4))) float f32x4;

__device__ __forceinline__ u16 f2bf(float f) {       // RNE
  uint32_t u = __float_as_uint(f);
  u += 0x7fffu + ((u >> 16) & 1u);
  return (u16)(u >> 16);
}
__device__ __forceinline__ float bf2f(u16 h) {
  return __uint_as_float(((uint32_t)h) << 16);
}
// hi = truncated top-16, lo = RNE remainder; ~2^-17 relative total error.
__device__ __forceinline__ void split2(float v, u16& h, u16& l) {
  uint32_t u = __float_as_uint(v);
  h = (u16)(u >> 16);
  float hf = __uint_as_float(u & 0xffff0000u);
  l = f2bf(v - hf);
}
__device__ __forceinline__ void gload16(const void* g, void* l) {
  __builtin_amdgcn_global_load_lds(
      (const __attribute__((address_space(1))) uint32_t*)g,
      (__attribute__((address_space(3))) uint32_t*)l, 16, 0, 0);
}

// =====================================================================
// Kernel 1a: per-chunk branchless top-3.  grid (M/256, SCH_), 256 thr.
// Distance arithmetic identical to rounds 1-5 (absmax anchor).
// Branchless insert == original strict-< insertion (ties: earlier j wins).
// =====================================================================
__global__ __launch_bounds__(256) void knn_kernel(
    const float* __restrict__ xyz1, const float* __restrict__ xyz2,
    float* __restrict__ candD, int* __restrict__ candI)
{
  __shared__ float4 s4[CPTS];      // 4 KB
  const int t  = threadIdx.x;
  const int q  = blockIdx.x * 256 + t;     // global query (one batch per block)
  const int b  = q >> 13;                  // N_ = 8192
  const int ch = blockIdx.y;
  const int jb = ch * CPTS;

  // stage chunk points (one per thread)
  {
    const float* p = xyz2 + ((size_t)b * S_ + jb + t) * 3;
    float px = p[0], py = p[1], pz = p[2];
    float nn = __fadd_rn(__fadd_rn(__fmul_rn(px, px), __fmul_rn(py, py)), __fmul_rn(pz, pz));
    s4[t] = make_float4(px, py, pz, nn);
  }
  __syncthreads();

  const float* p1 = xyz1 + (size_t)q * 3;
  const float ax = p1[0], ay = p1[1], az = p1[2];
  const float na = __fadd_rn(__fadd_rn(__fmul_rn(ax, ax), __fmul_rn(ay, ay)), __fmul_rn(az, az));

  float d0 = 3.0e38f, d1 = 3.0e38f, d2 = 3.0e38f;
  int   i0 = 0, i1 = 0, i2 = 0;
  #pragma unroll 4
  for (int j = 0; j < CPTS; ++j) {
    float4 p = s4[j];
    float ab = __fmaf_rn(az, p.z, __fmaf_rn(ay, p.y, __fmul_rn(ax, p.x)));
    float d  = __fadd_rn(__fadd_rn(na, p.w), __fmul_rn(-2.0f, ab));
    bool lt0 = d < d0, lt1 = d < d1, lt2 = d < d2;
    int  jg  = jb + j;
    d2 = lt1 ? d1 : (lt2 ? d : d2);  i2 = lt1 ? i1 : (lt2 ? jg : i2);
    d1 = lt0 ? d0 : (lt1 ? d : d1);  i1 = lt0 ? i0 : (lt1 ? jg : i1);
    d0 = lt0 ? d  : d0;              i0 = lt0 ? jg : i0;
  }
  candD[(size_t)(ch * 3 + 0) * M_ + q] = d0;
  candD[(size_t)(ch * 3 + 1) * M_ + q] = d1;
  candD[(size_t)(ch * 3 + 2) * M_ + q] = d2;
  candI[(size_t)(ch * 3 + 0) * M_ + q] = i0;
  candI[(size_t)(ch * 3 + 1) * M_ + q] = i1;
  candI[(size_t)(ch * 3 + 2) * M_ + q] = i2;
}

// =====================================================================
// Kernel 1b: merge 8x3 candidates (chunk-major order, strict <) -> weights.
// Faithful to single-pass selection: lower index arrives earlier on ties.
// =====================================================================
__global__ __launch_bounds__(256) void merge_kernel(
    const float* __restrict__ candD, const int* __restrict__ candI,
    float* __restrict__ wiW, int* __restrict__ wiI)
{
  const int q = blockIdx.x * 256 + threadIdx.x;
  float d0 = 3.0e38f, d1 = 3.0e38f, d2 = 3.0e38f;
  int   i0 = 0, i1 = 0, i2 = 0;
  #pragma unroll
  for (int s = 0; s < 3 * SCH_; ++s) {
    float d = candD[(size_t)s * M_ + q];
    int   i = candI[(size_t)s * M_ + q];
    bool lt0 = d < d0, lt1 = d < d1, lt2 = d < d2;
    d2 = lt1 ? d1 : (lt2 ? d : d2);  i2 = lt1 ? i1 : (lt2 ? i : i2);
    d1 = lt0 ? d0 : (lt1 ? d : d1);  i1 = lt0 ? i0 : (lt1 ? i : i1);
    d0 = lt0 ? d  : d0;              i0 = lt0 ? i : i0;
  }
  d0 = fmaxf(d0, 0.0f); d1 = fmaxf(d1, 0.0f); d2 = fmaxf(d2, 0.0f);
  float w0 = 1.0f / (d0 + 1e-8f);
  float w1 = 1.0f / (d1 + 1e-8f);
  float w2 = 1.0f / (d2 + 1e-8f);
  float ws = __fadd_rn(__fadd_rn(w0, w1), w2);
  wiW[q] = w0 / ws; wiW[M_ + q] = w1 / ws; wiW[2 * M_ + q] = w2 / ws;
  wiI[q] = i0;      wiI[M_ + q] = i1;      wiI[2 * M_ + q] = i2;
}

// =====================================================================
// Kernel 1c: gather + interpolate + concat -> xhl rows [hi384|lo384].
// 64 lanes per query (4 ch each, float4), 4 queries per block.
// =====================================================================
__global__ __launch_bounds__(256) void gather_kernel(
    const float* __restrict__ points1, const float* __restrict__ points2,
    const float* __restrict__ wiW, const int* __restrict__ wiI,
    u16* __restrict__ xhl)
{
  const int t = threadIdx.x;
  const int q = blockIdx.x * 4 + (t >> 6);
  const int c = t & 63;
  const int b = q >> 13;
  const int j0 = wiI[q], j1 = wiI[M_ + q], j2 = wiI[2 * M_ + q];
  const float v0 = wiW[q], v1 = wiW[M_ + q], v2 = wiW[2 * M_ + q];
  const float* p2b = points2 + (size_t)b * S_ * C2_;
  float4 r0 = *(const float4*)(p2b + (size_t)j0 * C2_ + 4 * c);
  float4 r1 = *(const float4*)(p2b + (size_t)j1 * C2_ + 4 * c);
  float4 r2 = *(const float4*)(p2b + (size_t)j2 * C2_ + 4 * c);
  u16* row = xhl + (size_t)q * 768;
  short4v hv, lv;
  {
    float f;
    u16 h, l;
    f = __fadd_rn(__fadd_rn(__fmul_rn(r0.x, v0), __fmul_rn(r1.x, v1)), __fmul_rn(r2.x, v2));
    split2(f, h, l); hv[0] = (short)h; lv[0] = (short)l;
    f = __fadd_rn(__fadd_rn(__fmul_rn(r0.y, v0), __fmul_rn(r1.y, v1)), __fmul_rn(r2.y, v2));
    split2(f, h, l); hv[1] = (short)h; lv[1] = (short)l;
    f = __fadd_rn(__fadd_rn(__fmul_rn(r0.z, v0), __fmul_rn(r1.z, v1)), __fmul_rn(r2.z, v2));
    split2(f, h, l); hv[2] = (short)h; lv[2] = (short)l;
    f = __fadd_rn(__fadd_rn(__fmul_rn(r0.w, v0), __fmul_rn(r1.w, v1)), __fmul_rn(r2.w, v2));
    split2(f, h, l); hv[3] = (short)h; lv[3] = (short)l;
  }
  *(short4v*)(row + 128 + 4 * c) = hv;        // hi of ch 128+4c
  *(short4v*)(row + 512 + 4 * c) = lv;        // lo at 384+128+4c
  if (c < 32) {                               // points1 -> ch 0..127
    float4 p = *(const float4*)(points1 + (size_t)q * C1_ + 4 * c);
    short4v ph, pl;
    u16 h, l;
    split2(p.x, h, l); ph[0] = (short)h; pl[0] = (short)l;
    split2(p.y, h, l); ph[1] = (short)h; pl[1] = (short)l;
    split2(p.z, h, l); ph[2] = (short)h; pl[2] = (short)l;
    split2(p.w, h, l); ph[3] = (short)h; pl[3] = (short)l;
    *(short4v*)(row + 4 * c) = ph;
    *(short4v*)(row + 384 + 4 * c) = pl;
  }
}

// =====================================================================
// Kernel 2: W1 fp32 -> [hi K | lo K] bf16 rows (written into d_out head)
// =====================================================================
__global__ __launch_bounds__(128) void wconv_kernel(
    const float* __restrict__ W, u16* __restrict__ Whl, int K)
{
  int c = blockIdx.x * 128 + threadIdx.x;
  int o = blockIdx.y;
  float w = W[(size_t)o * K + c];
  u16 h, l; split2(w, h, l);
  Whl[(size_t)o * 2 * K + c] = h;
  Whl[(size_t)o * 2 * K + K + c] = l;
}

// =====================================================================
// Kernel 3: bf16-split MFMA GEMM (m97 shape) — unchanged from round 5.
// =====================================================================
template<int K, bool BCONV>
__global__ __launch_bounds__(256) void gemm_kernel(
    const u16* __restrict__ A, const u16* __restrict__ Bu,
    const float* __restrict__ Bf, const float* __restrict__ bias,
    u16* __restrict__ Y, float* __restrict__ sumOut, float* __restrict__ sqOut)
{
  __shared__ __align__(16) u16 sAh[4096], sAl[4096], sBh[4096], sBl[4096]; // 8 KB each
  __shared__ float sred[256];
  static_assert(K % 32 == 0, "");

  const int t  = threadIdx.x;
  const int n0 = blockIdx.x * 128;
  const int m0 = blockIdx.y * 128;
  const int l  = t & 63, lr = l & 15, lq = l >> 4;
  const int wid = t >> 6, wm = wid >> 1, wn = wid & 1;

  f32x4 acc[4][4];
  #pragma unroll
  for (int i = 0; i < 4; ++i)
    #pragma unroll
    for (int j = 0; j < 4; ++j) acc[i][j] = (f32x4){0.f, 0.f, 0.f, 0.f};

  for (int kt = 0; kt < K; kt += 32) {
    #pragma unroll
    for (int i = 0; i < 2; ++i) {
      int u = i * 256 + t;
      int row = u >> 2, sl = u & 3;
      const u16* srcA = A + (size_t)(m0 + row) * (2 * K) + kt + sl * 8;
      gload16(srcA,     (char*)sAh + u * 16);
      gload16(srcA + K, (char*)sAl + u * 16);
      if constexpr (!BCONV) {
        const u16* srcB = Bu + (size_t)(n0 + row) * (2 * K) + kt + sl * 8;
        gload16(srcB,     (char*)sBh + u * 16);
        gload16(srcB + K, (char*)sBl + u * 16);
      }
    }
    if constexpr (BCONV) {
      #pragma unroll
      for (int i = 0; i < 4; ++i) {
        int u = i * 256 + t;
        int row = u >> 3, c4 = (u & 7) * 4;
        float4 w4 = *(const float4*)(Bf + (size_t)(n0 + row) * K + kt + c4);
        short4v h4, l4;
        u16 h, lo;
        split2(w4.x, h, lo); h4[0] = (short)h; l4[0] = (short)lo;
        split2(w4.y, h, lo); h4[1] = (short)h; l4[1] = (short)lo;
        split2(w4.z, h, lo); h4[2] = (short)h; l4[2] = (short)lo;
        split2(w4.w, h, lo); h4[3] = (short)h; l4[3] = (short)lo;
        *(short4v*)((char*)sBh + row * 64 + c4 * 2) = h4;
        *(short4v*)((char*)sBl + row * 64 + c4 * 2) = l4;
      }
    }
    __syncthreads();

    const int abase = (wm * 64 + lr) * 64 + lq * 16;   // byte offsets
    const int bbase = (wn * 64 + lr) * 64 + lq * 16;
    short8 bh[4], bl[4];
    #pragma unroll
    for (int ni = 0; ni < 4; ++ni) {
      bh[ni] = *(const short8*)((const char*)sBh + bbase + ni * 1024);
      bl[ni] = *(const short8*)((const char*)sBl + bbase + ni * 1024);
    }
    #pragma unroll
    for (int mi = 0; mi < 4; ++mi) {
      short8 ah = *(const short8*)((const char*)sAh + abase + mi * 1024);
      short8 al = *(const short8*)((const char*)sAl + abase + mi * 1024);
      #pragma unroll
      for (int ni = 0; ni < 4; ++ni) {
        acc[mi][ni] = __builtin_amdgcn_mfma_f32_16x16x32_bf16(ah, bh[ni], acc[mi][ni], 0, 0, 0);
        acc[mi][ni] = __builtin_amdgcn_mfma_f32_16x16x32_bf16(ah, bl[ni], acc[mi][ni], 0, 0, 0);
        acc[mi][ni] = __builtin_amdgcn_mfma_f32_16x16x32_bf16(al, bh[ni], acc[mi][ni], 0, 0, 0);
      }
    }
    __syncthreads();
  }

  // ---- epilogue: bias, hi/lo store, BN stats ----
  sred[t] = 0.f;
  __syncthreads();

  float bj[4];
  #pragma unroll
  for (int ni = 0; ni < 4; ++ni) bj[ni] = bias[n0 + wn * 64 + ni * 16 + lr];

  float colS[4] = {0.f, 0.f, 0.f, 0.f}, colQ[4] = {0.f, 0.f, 0.f, 0.f};
  #pragma unroll
  for (int mi = 0; mi < 4; ++mi) {
    #pragma unroll
    for (int q = 0; q < 4; ++q) {
      int m = m0 + wm * 64 + mi * 16 + lq * 4 + q;
      u16* yr = Y + (size_t)m * 1024 + n0;
      #pragma unroll
      for (int ni = 0; ni < 4; ++ni) {
        int col = wn * 64 + ni * 16 + lr;
        float v = acc[mi][ni][q] + bj[ni];
        u16 h, lo; split2(v, h, lo);
        yr[col] = h; yr[512 + col] = lo;
        colS[ni] += v;
        colQ[ni] = __fmaf_rn(v, v, colQ[ni]);
      }
    }
  }
  #pragma unroll
  for (int ni = 0; ni < 4; ++ni) {
    int col = wn * 64 + ni * 16 + lr;
    atomicAdd(&sred[col], colS[ni]);
    atomicAdd(&sred[128 + col], colQ[ni]);
  }
  __syncthreads();
  if (t < 128) {
    atomicAdd(&sumOut[n0 + t], sred[t]);
    atomicAdd(&sqOut[n0 + t], sred[128 + t]);
  }
}

// =====================================================================
// Kernel 4: BN stats -> scale/shift
// =====================================================================
__global__ void finalize_kernel(const float* __restrict__ sum, const float* __restrict__ sq,
                                const float* __restrict__ g, const float* __restrict__ be,
                                float* __restrict__ scale, float* __restrict__ shift)
{
  int c = blockIdx.x * 256 + threadIdx.x;
  if (c >= 512) return;
  const float invM = 1.0f / 65536.0f;
  float mean = sum[c] * invM;
  float var  = fmaxf(sq[c] * invM - mean * mean, 0.0f);
  float rstd = rsqrtf(var + 1e-5f);
  float sc   = g[c] * rstd;
  scale[c] = sc;
  shift[c] = __fmaf_rn(-mean, sc, be[c]);
}

// =====================================================================
// Kernel 5: x2 = relu(bn1(y1)) in-place on y1hl (hi/lo rows), re-split.
// =====================================================================
__global__ __launch_bounds__(256) void x2_kernel(
    u16* __restrict__ y, const float* __restrict__ sc, const float* __restrict__ sh)
{
  const int total8 = M_ * 512 / 8;
  for (int i8 = blockIdx.x * 256 + threadIdx.x; i8 < total8;
       i8 += gridDim.x * 256) {
    int row = i8 >> 6, c8 = (i8 & 63) * 8;
    u16* p = y + (size_t)row * 1024 + c8;
    short8 h8 = *(const short8*)p;
    short8 l8 = *(const short8*)(p + 512);
    float4 sc0 = *(const float4*)(sc + c8), sc1v = *(const float4*)(sc + c8 + 4);
    float4 sh0 = *(const float4*)(sh + c8), sh1v = *(const float4*)(sh + c8 + 4);
    float scv[8] = {sc0.x, sc0.y, sc0.z, sc0.w, sc1v.x, sc1v.y, sc1v.z, sc1v.w};
    float shv[8] = {sh0.x, sh0.y, sh0.z, sh0.w, sh1v.x, sh1v.y, sh1v.z, sh1v.w};
    short8 ho, lo_;
    #pragma unroll
    for (int j = 0; j < 8; ++j) {
      float v = bf2f((u16)h8[j]) + bf2f((u16)l8[j]);
      float z = fmaxf(__fmaf_rn(v, scv[j], shv[j]), 0.0f);
      u16 h, lo; split2(z, h, lo);
      ho[j] = (short)h; lo_[j] = (short)lo;
    }
    *(short8*)p = ho;
    *(short8*)(p + 512) = lo_;
  }
}

// =====================================================================
// Kernel 6: final BN+ReLU, in-place (u16 hi/lo row -> fp32 row).
// =====================================================================
__global__ __launch_bounds__(256) void bnrelu_kernel(
    u16* __restrict__ y, const float* __restrict__ sc, const float* __restrict__ sh)
{
  const size_t row = blockIdx.x;
  u16* ru = y + row * 1024;
  const int t = threadIdx.x;
  u16 h0 = ru[2 * t], h1 = ru[2 * t + 1];
  u16 l0 = ru[512 + 2 * t], l1 = ru[512 + 2 * t + 1];
  float2 scv = *(const float2*)(sc + 2 * t);
  float2 shv = *(const float2*)(sh + 2 * t);
  float v0 = bf2f(h0) + bf2f(l0);
  float v1 = bf2f(h1) + bf2f(l1);
  float o0 = fmaxf(__fmaf_rn(v0, scv.x, shv.x), 0.0f);
  float o1 = fmaxf(__fmaf_rn(v1, scv.y, shv.y), 0.0f);
  __syncthreads();
  *(float2*)((float*)ru + 2 * t) = make_float2(o0, o1);
}

// =====================================================================
extern "C" void kernel_launch(void* const* d_in, const int* in_sizes, int n_in,
                              void* d_out, int out_size, void* d_ws, size_t ws_size,
                              hipStream_t stream)
{
  const float* xyz1    = (const float*)d_in[0];
  const float* xyz2    = (const float*)d_in[1];
  const float* points1 = (const float*)d_in[2];
  const float* points2 = (const float*)d_in[3];
  const float* W1  = (const float*)d_in[4];
  const float* b1  = (const float*)d_in[5];
  const float* g1  = (const float*)d_in[6];
  const float* be1 = (const float*)d_in[7];
  const float* W2  = (const float*)d_in[8];
  const float* b2  = (const float*)d_in[9];
  const float* g2  = (const float*)d_in[10];
  const float* be2 = (const float*)d_in[11];

  // ws: stats (16 KB) + y1hl (134.22 MB) — same footprint as round 5 (proven)
  float* wsf = (float*)d_ws;
  float* sum1 = wsf + 0,    *sq1 = wsf + 512,  *sc1 = wsf + 1024, *sh1 = wsf + 1536;
  float* sum2 = wsf + 2048, *sq2 = wsf + 2560, *sc2 = wsf + 3072, *sh2 = wsf + 3584;
  u16* y1hl = (u16*)((char*)d_ws + 16384);      // M x [hi512|lo512]

  // d_out staging (134,217,728 B total):
  //   w1hl  [0,          786,432)
  //   xhl   [786,432,    101,449,728)
  //   candD [101,449,728, 107,741,184)   24 x M floats
  //   candI [107,741,184, 114,032,640)   24 x M ints
  //   wiW   [114,032,640, 114,819,072)    3 x M floats
  //   wiI   [114,819,072, 115,605,504)    3 x M ints
  char* ob = (char*)d_out;
  u16*   w1hl = (u16*)ob;
  u16*   xhl  = (u16*)(ob + 786432);
  float* candD = (float*)(ob + 101449728);
  int*   candI = (int*)(ob + 107741184);
  float* wiW   = (float*)(ob + 114032640);
  int*   wiI   = (int*)(ob + 114819072);

  hipMemsetAsync(d_ws, 0, 16384, stream);

  wconv_kernel<<<dim3(CIN_ / 128, 512), 128, 0, stream>>>(W1, w1hl, CIN_);

  knn_kernel<<<dim3(M_ / 256, SCH_), 256, 0, stream>>>(xyz1, xyz2, candD, candI);
  merge_kernel<<<M_ / 256, 256, 0, stream>>>(candD, candI, wiW, wiI);
  gather_kernel<<<M_ / 4, 256, 0, stream>>>(points1, points2, wiW, wiI, xhl);

  gemm_kernel<CIN_, false><<<dim3(4, M_ / 128), 256, 0, stream>>>(
      xhl, w1hl, nullptr, b1, y1hl, sum1, sq1);

  finalize_kernel<<<2, 256, 0, stream>>>(sum1, sq1, g1, be1, sc1, sh1);

  x2_kernel<<<2048, 256, 0, stream>>>(y1hl, sc1, sh1);

  gemm_kernel<NOUT_, true><<<dim3(4, M_ / 128), 256, 0, stream>>>(
      y1hl, nullptr, W2, b2, (u16*)d_out, sum2, sq2);

  finalize_kernel<<<2, 256, 0, stream>>>(sum2, sq2, g2, be2, sc2, sh2);

  bnrelu_kernel<<<M_, 256, 0, stream>>>((u16*)d_out, sc2, sh2);
}